// Round 8
// baseline (1067.306 us; speedup 1.0000x reference)
//
#include <hip/hip_runtime.h>

#define DM 128          // model dim
#define KS 20           // attention samples
#define BW 512          // CSR bucket width (nodes)
#define BSH 9           // log2(BW)
#define MAXB 128        // max buckets (N <= 65536)
#define HP 520          // padded LDS hidden row stride (ffn full-width), 16B-aligned

typedef __attribute__((ext_vector_type(8))) short short8;   // 8 bf16 (4 VGPRs)
typedef __attribute__((ext_vector_type(4))) float f32x4;
typedef __attribute__((ext_vector_type(2))) float f32x2;
typedef __attribute__((ext_vector_type(2))) __bf16 bf16x2;

__device__ __forceinline__ unsigned short f2b(float f) {
    unsigned u = __float_as_uint(f);
    u += 0x7fff + ((u >> 16) & 1);          // RNE
    return (unsigned short)(u >> 16);
}
__device__ __forceinline__ float b2f(unsigned short b) {
    return __uint_as_float(((unsigned)b) << 16);
}
__device__ __forceinline__ float blo(unsigned u) { return __uint_as_float(u << 16); }
__device__ __forceinline__ float bhi(unsigned u) { return __uint_as_float(u & 0xffff0000u); }
__device__ __forceinline__ unsigned pk(float a, float b) {
    return (unsigned)f2b(a) | ((unsigned)f2b(b) << 16);
}

// Packed bf16 dot-2 (HW v_dot2_f32_bf16 when available; fallback compile-safe)
#if __has_builtin(__builtin_amdgcn_fdot2_f32_bf16)
__device__ __forceinline__ float dot2bf(unsigned a, unsigned b, float acc) {
    return __builtin_amdgcn_fdot2_f32_bf16(
        __builtin_bit_cast(bf16x2, a), __builtin_bit_cast(bf16x2, b), acc, false);
}
#else
__device__ __forceinline__ float dot2bf(unsigned a, unsigned b, float acc) {
    return acc + blo(a) * blo(b) + bhi(a) * bhi(b);
}
#endif

// ---------------- fp8 e4m3 helpers (HW cvt on gfx950; SW fallback) ----------
__device__ __forceinline__ float f8dec_sw(unsigned char b) {
    const int s = b >> 7, e = (b >> 3) & 15, m = b & 7;
    float v = e ? ldexpf((float)(8 + m), e - 10) : ldexpf((float)m, -9);
    return s ? -v : v;
}
// decode 2 fp8 from low/high 16-bit word of u (HI must be compile-time const)
template <bool HI>
__device__ __forceinline__ f32x2 fp8x2(unsigned u) {
#if __has_builtin(__builtin_amdgcn_cvt_pk_f32_fp8)
    return __builtin_amdgcn_cvt_pk_f32_fp8(u, HI);
#else
    const unsigned w = HI ? (u >> 16) : (u & 0xffffu);
    return (f32x2){f8dec_sw((unsigned char)(w & 0xff)),
                   f8dec_sw((unsigned char)(w >> 8))};
#endif
}
__device__ __forceinline__ unsigned char f8enc(float v) {
#if __has_builtin(__builtin_amdgcn_cvt_pk_fp8_f32)
    return (unsigned char)(__builtin_amdgcn_cvt_pk_fp8_f32(v, v, 0, false) & 0xff);
#else
    unsigned u = __float_as_uint(v);
    unsigned s = (u >> 24) & 0x80;
    unsigned a = u & 0x7fffffffu;
    if (a >= 0x43e00000u) return (unsigned char)(s | 0x7e);   // clamp to 448
    if (a < 0x3c000000u) {                                    // subnormal (<2^-7 approx)
        int r = (int)(__uint_as_float(a) * 512.f + 0.5f);
        if (r > 7) return (unsigned char)(s | 0x08);
        return (unsigned char)(s | (unsigned)r);
    }
    unsigned r = a + 0x7ffffu + ((a >> 20) & 1);              // RNE at bit 20
    unsigned e = (r >> 23) - 120;
    unsigned m = (r >> 20) & 7;
    return (unsigned char)(s | (e << 3) | m);
#endif
}

// ---------------------------------------------------------------------------
// x -> h (fp32 copy) + hb (bf16), float4 wide
// ---------------------------------------------------------------------------
__global__ __launch_bounds__(256) void xcvt_kernel(
    const float* __restrict__ x, float* __restrict__ h,
    unsigned short* __restrict__ hb, int n)
{
    const int i = (blockIdx.x * 256 + threadIdx.x) * 4;
    if (i < n) {
        const float4 v = *(const float4*)(x + i);
        *(float4*)(h + i) = v;
        ((unsigned*)hb)[i / 2]     = pk(v.x, v.y);
        ((unsigned*)hb)[i / 2 + 1] = pk(v.z, v.w);
    }
}

// ---------------------------------------------------------------------------
// Merged setup (R15): weight bf16 convert + WoP repack + bcnt zero.
// ---------------------------------------------------------------------------
__global__ __launch_bounds__(256) void setup_kernel(
    const float* __restrict__ t_in_w,  const float* __restrict__ t_out_w,
    const float* __restrict__ t_ffn_w1, const float* __restrict__ t_ffn_w2,
    const float* __restrict__ g_w, unsigned short* __restrict__ wbuf,
    unsigned* __restrict__ WoP, int* __restrict__ bcnt)
{
    const int tid = blockIdx.x * 256 + threadIdx.x;
    if (tid < 163840) {
        const int i4 = tid * 4;
        const float* src; int rel;
        if      (i4 < 147456) { src = t_in_w;   rel = i4; }
        else if (i4 < 196608) { src = t_out_w;  rel = i4 - 147456; }
        else if (i4 < 393216) { src = t_ffn_w1; rel = i4 - 196608; }
        else if (i4 < 589824) { src = t_ffn_w2; rel = i4 - 393216; }
        else                  { src = g_w;      rel = i4 - 589824; }
        const float4 v = *(const float4*)(src + rel);
        ((unsigned*)wbuf)[i4 / 2]     = pk(v.x, v.y);
        ((unsigned*)wbuf)[i4 / 2 + 1] = pk(v.z, v.w);
    } else if (tid < 163840 + 24576) {
        const int t2 = tid - 163840;
        const int i = t2 / 8192, rem = t2 % 8192;
        const int plane = rem >> 12, r2 = rem & 4095;
        const int k2 = r2 >> 6, j = r2 & 63;
        const int col = j + plane * 64;
        const float* W = t_out_w + (size_t)i * 16384;   // [128][128]
        WoP[(size_t)i * 8192 + plane * 4096 + k2 * 64 + j] =
            pk(W[col * 128 + 2 * k2], W[col * 128 + 2 * k2 + 1]);
    } else if (tid < 163840 + 24576 + MAXB) {
        bcnt[tid - 163840 - 24576] = 0;
    }
}

// ---------------------------------------------------------------------------
// QKV GEMM (R16): out = X@W^T + bias, CI=128, CO=384.
// Band 0-1 (cols 0..127 = Q)   -> Qbf bf16 [N][128]
// Band 2-5 (cols 128..383 = KV)-> kv8 fp8 e4m3 [N][256] (K bytes 0-127, V 128-255)
// ---------------------------------------------------------------------------
__global__ __launch_bounds__(256) void gemm_qkv(
    const unsigned short* __restrict__ X,
    const unsigned short* __restrict__ W, const float* __restrict__ bias,
    unsigned short* __restrict__ Qbf, unsigned char* __restrict__ kv8, int M)
{
    const int tid  = threadIdx.x;
    const int wave = tid >> 6;
    const int lane = tid & 63;
    const int m0 = blockIdx.x * 128 + (wave >> 1) * 64;
    const int c0 = blockIdx.y * 64 + (wave & 1) * 32;
    const int lrow = lane & 15;
    const int quad = lane >> 4;

    f32x4 acc[4][2];
    #pragma unroll
    for (int i = 0; i < 4; ++i)
        #pragma unroll
        for (int j = 0; j < 2; ++j)
            acc[i][j] = (f32x4){0.f, 0.f, 0.f, 0.f};

    int rr[4]; bool vv[4];
    #pragma unroll
    for (int i = 0; i < 4; ++i) { rr[i] = m0 + i * 16 + lrow; vv[i] = rr[i] < M; }

    #pragma unroll
    for (int k0 = 0; k0 < 128; k0 += 32) {
        const int ko = k0 + quad * 8;
        short8 a[4];
        #pragma unroll
        for (int i = 0; i < 4; ++i) {
            a[i] = short8{};
            if (vv[i]) a[i] = *(const short8*)(X + (size_t)rr[i] * 128 + ko);
        }
        const short8 b0 = *(const short8*)(W + (size_t)(c0 + lrow) * 128 + ko);
        const short8 b1 = *(const short8*)(W + (size_t)(c0 + 16 + lrow) * 128 + ko);
        #pragma unroll
        for (int i = 0; i < 4; ++i) {
            acc[i][0] = __builtin_amdgcn_mfma_f32_16x16x32_bf16(a[i], b0, acc[i][0], 0, 0, 0);
            acc[i][1] = __builtin_amdgcn_mfma_f32_16x16x32_bf16(a[i], b1, acc[i][1], 0, 0, 0);
        }
    }

    const bool isQ = (c0 < 128);   // uniform per block (band granularity = 64 cols)
    #pragma unroll
    for (int i = 0; i < 4; ++i) {
        const int rb = m0 + i * 16 + quad * 4;
        #pragma unroll
        for (int j = 0; j < 2; ++j) {
            const int col = c0 + j * 16 + lrow;
            const float bsv = bias[col];
            #pragma unroll
            for (int r = 0; r < 4; ++r) {
                const int row = rb + r;
                if (row < M) {
                    const float v = acc[i][j][r] + bsv;
                    if (isQ) Qbf[(size_t)row * 128 + col] = f2b(v);
                    else     kv8[(size_t)row * 256 + (col - 128)] = f8enc(v);
                }
            }
        }
    }
}

// ---------------------------------------------------------------------------
// Fused GEMM(CO=128) + residual + LayerNorm. (verified R3-R8)
// ---------------------------------------------------------------------------
template <int CI, bool RELU, int SPLIT>
__global__ __launch_bounds__(256) void gemm_ln(
    const unsigned short* __restrict__ X0, const unsigned short* __restrict__ X1,
    const unsigned short* __restrict__ W, const float* __restrict__ bias,
    const float* __restrict__ resid,
    const float* __restrict__ g, const float* __restrict__ be,
    float* __restrict__ hF, unsigned short* __restrict__ hB, int M)
{
    __shared__ float psum[64][2][2];
    __shared__ float stats[64][2];

    const int tid  = threadIdx.x;
    const int wave = tid >> 6;
    const int lane = tid & 63;
    const int wr = (wave >> 1) * 32;
    const int wc = wave & 1;
    const int m0 = blockIdx.x * 64 + wr;
    const int c0 = wc * 64;
    const int lrow = lane & 15;
    const int quad = lane >> 4;

    f32x4 acc[2][4];
    #pragma unroll
    for (int i = 0; i < 2; ++i)
        #pragma unroll
        for (int j = 0; j < 4; ++j)
            acc[i][j] = (f32x4){0.f, 0.f, 0.f, 0.f};

    const int r0 = m0 + lrow;
    const int r1 = m0 + 16 + lrow;
    const bool v0 = r0 < M, v1 = r1 < M;

    for (int k0 = 0; k0 < CI; k0 += 32) {
        const unsigned short* xs;
        int kk, stride;
        if (SPLIT > 0 && k0 >= SPLIT) { xs = X1; kk = k0 - SPLIT; stride = CI - SPLIT; }
        else                          { xs = X0; kk = k0;         stride = (SPLIT > 0) ? SPLIT : CI; }
        const int ko = kk + quad * 8;
        short8 a0 = {}, a1 = {};
        if (v0) a0 = *(const short8*)(xs + (size_t)r0 * stride + ko);
        if (v1) a1 = *(const short8*)(xs + (size_t)r1 * stride + ko);
        const int kw = k0 + quad * 8;
        #pragma unroll
        for (int j = 0; j < 4; ++j) {
            const short8 bf = *(const short8*)(W + (size_t)(c0 + j * 16 + lrow) * CI + kw);
            acc[0][j] = __builtin_amdgcn_mfma_f32_16x16x32_bf16(a0, bf, acc[0][j], 0, 0, 0);
            acc[1][j] = __builtin_amdgcn_mfma_f32_16x16x32_bf16(a1, bf, acc[1][j], 0, 0, 0);
        }
    }

    float bcol[4], gcol[4], bec[4];
    #pragma unroll
    for (int j = 0; j < 4; ++j) {
        const int col = c0 + j * 16 + lrow;
        bcol[j] = bias[col];
        gcol[j] = g[col];
        bec[j]  = be[col];
    }

    float vals[2][4][4];
    #pragma unroll
    for (int i = 0; i < 2; ++i) {
        #pragma unroll
        for (int r = 0; r < 4; ++r) {
            const int lrel = wr + i * 16 + quad * 4 + r;
            const int row = blockIdx.x * 64 + lrel;
            const bool vr = row < M;
            float s = 0.f, s2 = 0.f;
            #pragma unroll
            for (int j = 0; j < 4; ++j) {
                const int col = c0 + j * 16 + lrow;
                float v = acc[i][j][r] + bcol[j];
                if (RELU) v = fmaxf(v, 0.f);
                if (vr) v += resid[(size_t)row * 128 + col];
                vals[i][j][r] = v;
                s += v; s2 += v * v;
            }
            s  += __shfl_xor(s, 1);  s  += __shfl_xor(s, 2);
            s  += __shfl_xor(s, 4);  s  += __shfl_xor(s, 8);
            s2 += __shfl_xor(s2, 1); s2 += __shfl_xor(s2, 2);
            s2 += __shfl_xor(s2, 4); s2 += __shfl_xor(s2, 8);
            if (lrow == 0) { psum[lrel][wc][0] = s; psum[lrel][wc][1] = s2; }
        }
    }
    __syncthreads();
    if (tid < 64) {
        const float sum   = psum[tid][0][0] + psum[tid][1][0];
        const float sumsq = psum[tid][0][1] + psum[tid][1][1];
        const float mean = sum * (1.f / 128.f);
        const float var  = sumsq * (1.f / 128.f) - mean * mean;
        stats[tid][0] = mean;
        stats[tid][1] = rsqrtf(var + 1e-5f);
    }
    __syncthreads();

    #pragma unroll
    for (int i = 0; i < 2; ++i) {
        #pragma unroll
        for (int r = 0; r < 4; ++r) {
            const int lrel = wr + i * 16 + quad * 4 + r;
            const int row = blockIdx.x * 64 + lrel;
            if (row < M) {
                const float mean = stats[lrel][0];
                const float rstd = stats[lrel][1];
                #pragma unroll
                for (int j = 0; j < 4; ++j) {
                    const int col = c0 + j * 16 + lrow;
                    const float o = (vals[i][j][r] - mean) * rstd * gcol[j] + bec[j];
                    hF[(size_t)row * 128 + col] = o;
                    hB[(size_t)row * 128 + col] = f2b(o);
                }
            }
        }
    }
}

// ---------------------------------------------------------------------------
// Fused FFN v7 (R22): out = LN( relu(X@W1^T+b1)@W2^T + b2 + resid ).
// v6 was latency-bound at 4 blocks/CU (LDS 34.6KB) with only ~6 blocks/CU of
// total work. v7: 16-row tiles -> Hs 16.6KB -> 8 blocks/CU (8 waves/SIMD,
// HW max), grid 1563->3125. TLP instead of ILP. Same 1-barrier structure,
// same per-column math. __launch_bounds__(256,8) caps VGPR at 64 (v6 fit 64
// with 2x the live state).
// ---------------------------------------------------------------------------
__global__ __launch_bounds__(256, 8) void ffn_fused(
    const unsigned short* __restrict__ X,    // [M][128] bf16
    const unsigned short* __restrict__ W1,   // [512][128]
    const float* __restrict__ b1,
    const unsigned short* __restrict__ W2,   // [128][512]
    const float* __restrict__ b2,
    const float* __restrict__ resid,
    const float* __restrict__ g, const float* __restrict__ be,
    float* __restrict__ hF, unsigned short* __restrict__ hB, int M)
{
    __shared__ unsigned short Hs[16 * HP];   // 16.6 KB full-width hidden buffer
    __shared__ float psum[16][4][2];
    __shared__ float stats[16][2];

    const int tid  = threadIdx.x;
    const int wave = tid >> 6;
    const int lane = tid & 63;
    const int lrow = lane & 15;
    const int quad = lane >> 4;
    const int m0 = blockIdx.x * 16;

    const int c0 = wave * 32;                // phase-2 col base (32 cols/wave)

    const int r0 = m0 + lrow;
    const bool v0 = r0 < M;

    // ---- hoisted X fragment loads: 4 x short8, all K ----
    short8 xa[4];
    #pragma unroll
    for (int k = 0; k < 4; ++k) {
        const int ko = k * 32 + quad * 8;
        xa[k] = short8{};
        if (v0) xa[k] = *(const short8*)(X + (size_t)r0 * 128 + ko);
    }

    // ---- hoisted residual loads (own rows only; in-place safe) ----
    float res[4][2];
    #pragma unroll
    for (int r = 0; r < 4; ++r) {
        const int row = m0 + quad * 4 + r;
        const bool vr = row < M;
        #pragma unroll
        for (int j = 0; j < 2; ++j)
            res[r][j] = vr ? resid[(size_t)row * 128 + c0 + j * 16 + lrow] : 0.f;
    }

    // ---- phase 1: all 512 hidden cols, no intervening barrier ----
    #pragma unroll
    for (int half = 0; half < 2; ++half) {
        const int cb = half * 256 + wave * 64;    // global hidden col base
        f32x4 acc[4];
        #pragma unroll
        for (int j = 0; j < 4; ++j)
            acc[j] = (f32x4){0.f, 0.f, 0.f, 0.f};

        #pragma unroll
        for (int k = 0; k < 4; ++k) {
            const int ko = k * 32 + quad * 8;
            #pragma unroll
            for (int j = 0; j < 4; ++j) {
                const short8 bf = *(const short8*)(W1 + (size_t)(cb + j * 16 + lrow) * 128 + ko);
                acc[j] = __builtin_amdgcn_mfma_f32_16x16x32_bf16(xa[k], bf, acc[j], 0, 0, 0);
            }
        }
        float bc[4];
        #pragma unroll
        for (int j = 0; j < 4; ++j) bc[j] = b1[cb + j * 16 + lrow];
        #pragma unroll
        for (int r = 0; r < 4; ++r) {
            const int lrel = quad * 4 + r;
            #pragma unroll
            for (int j = 0; j < 4; ++j)
                Hs[lrel * HP + cb + j * 16 + lrow] =
                    f2b(fmaxf(acc[j][r] + bc[j], 0.f));
        }
    }
    __syncthreads();

    // ---- phase 2: full K=512 accumulation in one chain ----
    f32x4 acc2[2];
    acc2[0] = (f32x4){0.f, 0.f, 0.f, 0.f};
    acc2[1] = (f32x4){0.f, 0.f, 0.f, 0.f};

    #pragma unroll
    for (int k0 = 0; k0 < 512; k0 += 32) {
        const int ko = k0 + quad * 8;
        const short8 a0 = *(const short8*)&Hs[lrow * HP + ko];
        #pragma unroll
        for (int j = 0; j < 2; ++j) {
            const short8 bf = *(const short8*)(W2 + (size_t)(c0 + j * 16 + lrow) * 512 + ko);
            acc2[j] = __builtin_amdgcn_mfma_f32_16x16x32_bf16(a0, bf, acc2[j], 0, 0, 0);
        }
    }

    float bcol[2], gcol[2], bec[2];
    #pragma unroll
    for (int j = 0; j < 2; ++j) {
        const int col = c0 + j * 16 + lrow;
        bcol[j] = b2[col];
        gcol[j] = g[col];
        bec[j]  = be[col];
    }

    float vals[2][4];
    #pragma unroll
    for (int r = 0; r < 4; ++r) {
        const int lrel = quad * 4 + r;
        float s = 0.f, s2 = 0.f;
        #pragma unroll
        for (int j = 0; j < 2; ++j) {
            float v = acc2[j][r] + bcol[j] + res[r][j];
            vals[j][r] = v;
            s += v; s2 += v * v;
        }
        s  += __shfl_xor(s, 1);  s  += __shfl_xor(s, 2);
        s  += __shfl_xor(s, 4);  s  += __shfl_xor(s, 8);
        s2 += __shfl_xor(s2, 1); s2 += __shfl_xor(s2, 2);
        s2 += __shfl_xor(s2, 4); s2 += __shfl_xor(s2, 8);
        if (lrow == 0) { psum[lrel][wave][0] = s; psum[lrel][wave][1] = s2; }
    }
    __syncthreads();
    if (tid < 16) {
        const float sum   = psum[tid][0][0] + psum[tid][1][0] + psum[tid][2][0] + psum[tid][3][0];
        const float sumsq = psum[tid][0][1] + psum[tid][1][1] + psum[tid][2][1] + psum[tid][3][1];
        const float mean = sum * (1.f / 128.f);
        const float var  = sumsq * (1.f / 128.f) - mean * mean;
        stats[tid][0] = mean;
        stats[tid][1] = rsqrtf(var + 1e-5f);
    }
    __syncthreads();

    #pragma unroll
    for (int r = 0; r < 4; ++r) {
        const int lrel = quad * 4 + r;
        const int row = m0 + lrel;
        if (row < M) {
            const float mean = stats[lrel][0];
            const float rstd = stats[lrel][1];
            #pragma unroll
            for (int j = 0; j < 2; ++j) {
                const int col = c0 + j * 16 + lrow;
                const float o = (vals[j][r] - mean) * rstd * gcol[j] + bec[j];
                hF[(size_t)row * 128 + col] = o;
                hB[(size_t)row * 128 + col] = f2b(o);
            }
        }
    }
}

// ---------------------------------------------------------------------------
// attn_fused (R19, verified 79.5us; reverted from R21 whose LDS Wo staging
// had 8-way bank conflicts — 9.6M conflict cycles, occupancy 40%).
// Sampled attention (fp8 KV gather) + MFMA out-proj (padded ctxs,
// replicated-row all-lane epilogue) + resid + LN1.
// ---------------------------------------------------------------------------
__global__ __launch_bounds__(256) void attn_fused(
    const unsigned short* __restrict__ qbf,   // [N][128] bf16 Q
    const unsigned char* __restrict__ kv8,    // [N][256] fp8 (K 0-127 | V 128-255)
    const int* __restrict__ samples,
    const unsigned short* __restrict__ Wo,    // [128 col][128 k] bf16 out-proj
    const float* __restrict__ bo,
    const float* __restrict__ g, const float* __restrict__ be,
    float* __restrict__ hF, unsigned short* __restrict__ hB, int n)
{
    __shared__ unsigned ctxs[4][68];    // padded: rows on distinct bank groups
    __shared__ float psum[4][4][2];     // [node][wave][sum,sumsq]
    __shared__ float stats[4][2];
    const int wv = threadIdx.x >> 6;
    const int lane = threadIdx.x & 63;
    const int node0 = blockIdx.x * 4 + wv;
    const bool live = node0 < n;
    const int node = live ? node0 : (n - 1);   // clamp; stores guarded
    const int s4 = lane >> 4;
    const int p  = lane & 15;
    const float scale = 0.17677669529663687f;  // 1/sqrt(32)

    // ---- epilogue identity for this lane: node = quad (replicated C rows) --
    const int nd = blockIdx.x * 4 + s4;
    const bool alive = nd < n;
    const int col0 = wv * 32 + p;
    const int col1 = wv * 32 + 16 + p;
    // prefetch own-node residual (consumed after MFMA; in-place safe)
    float res0 = 0.f, res1 = 0.f;
    if (alive) {
        res0 = hF[(size_t)nd * 128 + col0];
        res1 = hF[(size_t)nd * 128 + col1];
    }

    const uint4 qu = *(const uint4*)(qbf + (size_t)node * 128 + p * 8);

    int rows[5];
    #pragma unroll
    for (int jj = 0; jj < 5; ++jj)
        rows[jj] = samples[node * KS + jj * 4 + s4];

    uint2 kus[5], vus[5];
    #pragma unroll
    for (int jj = 0; jj < 5; ++jj) {
        const unsigned char* rb = kv8 + (size_t)rows[jj] * 256 + p * 8;
        kus[jj] = *(const uint2*)rb;            // k dims 8p..8p+7 (fp8)
        vus[jj] = *(const uint2*)(rb + 128);    // v dims 8p..8p+7 (fp8)
    }

    // unpack own q once (dims 8p..8p+7)
    const float q0 = blo(qu.x), q1 = bhi(qu.x), q2 = blo(qu.y), q3 = bhi(qu.y);
    const float q4 = blo(qu.z), q5 = bhi(qu.z), q6 = blo(qu.w), q7 = bhi(qu.w);

    float sc[5];
    #pragma unroll
    for (int jj = 0; jj < 5; ++jj) {
        const f32x2 k0 = fp8x2<false>(kus[jj].x);   // dims 8p,   8p+1
        const f32x2 k1 = fp8x2<true >(kus[jj].x);   // dims 8p+2, 8p+3
        const f32x2 k2 = fp8x2<false>(kus[jj].y);   // dims 8p+4, 8p+5
        const f32x2 k3 = fp8x2<true >(kus[jj].y);   // dims 8p+6, 8p+7
        float d = q0 * k0.x;
        d = fmaf(q1, k0.y, d); d = fmaf(q2, k1.x, d); d = fmaf(q3, k1.y, d);
        d = fmaf(q4, k2.x, d); d = fmaf(q5, k2.y, d);
        d = fmaf(q6, k3.x, d); d = fmaf(q7, k3.y, d);
        d += __shfl_xor(d, 1);
        d += __shfl_xor(d, 2);
        sc[jj] = d * scale;
    }

    float m = sc[0];
    #pragma unroll
    for (int jj = 1; jj < 5; ++jj) m = fmaxf(m, sc[jj]);
    m = fmaxf(m, __shfl_xor(m, 16));
    m = fmaxf(m, __shfl_xor(m, 32));

    float l = 0.f;
    float o[8] = {};
    #pragma unroll
    for (int jj = 0; jj < 5; ++jj) {
        const float e = __expf(sc[jj] - m);
        l += e;
        const f32x2 v0 = fp8x2<false>(vus[jj].x);
        const f32x2 v1 = fp8x2<true >(vus[jj].x);
        const f32x2 v2 = fp8x2<false>(vus[jj].y);
        const f32x2 v3 = fp8x2<true >(vus[jj].y);
        o[0] = fmaf(e, v0.x, o[0]); o[1] = fmaf(e, v0.y, o[1]);
        o[2] = fmaf(e, v1.x, o[2]); o[3] = fmaf(e, v1.y, o[3]);
        o[4] = fmaf(e, v2.x, o[4]); o[5] = fmaf(e, v2.y, o[5]);
        o[6] = fmaf(e, v3.x, o[6]); o[7] = fmaf(e, v3.y, o[7]);
    }

    l += __shfl_xor(l, 16); l += __shfl_xor(l, 32);
    #pragma unroll
    for (int i = 0; i < 8; ++i) {
        o[i] += __shfl_xor(o[i], 16);
        o[i] += __shfl_xor(o[i], 32);
    }

    const float inv = 1.f / l;
    if (s4 == 0) {
        #pragma unroll
        for (int i = 0; i < 4; ++i)
            ctxs[wv][p * 4 + i] = pk(o[2 * i] * inv, o[2 * i + 1] * inv);
    }
    __syncthreads();

    // ---- out-proj via MFMA: rows 0-15 replicate nodes 0-3 ----
    // A-frag: lane row = p, supplies ctx[p&3], k = kt*32 + s4*8 .. +7
    // B-frag: col = wv*32 + j*16 + p, k consecutive (Wo row-major [col][k])
    f32x4 acc[2];
    acc[0] = (f32x4){0.f, 0.f, 0.f, 0.f};
    acc[1] = (f32x4){0.f, 0.f, 0.f, 0.f};
    #pragma unroll
    for (int kt = 0; kt < 4; ++kt) {
        const uint4 av = *(const uint4*)&ctxs[p & 3][kt * 16 + s4 * 4];
        const short8 af = __builtin_bit_cast(short8, av);
        #pragma unroll
        for (int j = 0; j < 2; ++j) {
            const int cb = wv * 32 + j * 16;
            const short8 bf = *(const short8*)(Wo + (size_t)(cb + p) * 128 + kt * 32 + s4 * 8);
            acc[j] = __builtin_amdgcn_mfma_f32_16x16x32_bf16(af, bf, acc[j], 0, 0, 0);
        }
    }

    // ---- all-lane epilogue: C row s4*4+r = node r; this lane keeps r = s4 --
    const float a0 = (s4 == 0) ? acc[0][0] : (s4 == 1) ? acc[0][1]
                   : (s4 == 2) ? acc[0][2] : acc[0][3];
    const float a1 = (s4 == 0) ? acc[1][0] : (s4 == 1) ? acc[1][1]
                   : (s4 == 2) ? acc[1][2] : acc[1][3];
    const float v0 = a0 + bo[col0] + res0;
    const float v1 = a1 + bo[col1] + res1;
    float s  = v0 + v1;
    float s2 = v0 * v0 + v1 * v1;
    s  += __shfl_xor(s, 1);  s  += __shfl_xor(s, 2);
    s  += __shfl_xor(s, 4);  s  += __shfl_xor(s, 8);
    s2 += __shfl_xor(s2, 1); s2 += __shfl_xor(s2, 2);
    s2 += __shfl_xor(s2, 4); s2 += __shfl_xor(s2, 8);
    if (p == 0) { psum[s4][wv][0] = s; psum[s4][wv][1] = s2; }
    __syncthreads();
    if (threadIdx.x < 4) {
        const int r = threadIdx.x;
        const float sum   = psum[r][0][0] + psum[r][1][0] + psum[r][2][0] + psum[r][3][0];
        const float sumsq = psum[r][0][1] + psum[r][1][1] + psum[r][2][1] + psum[r][3][1];
        const float mean = sum * (1.f / 128.f);
        const float var  = sumsq * (1.f / 128.f) - mean * mean;
        stats[r][0] = mean;
        stats[r][1] = rsqrtf(var + 1e-5f);
    }
    __syncthreads();
    if (alive) {
        const float mean = stats[s4][0];
        const float rstd = stats[s4][1];
        const float o0 = (v0 - mean) * rstd * g[col0] + be[col0];
        const float o1 = (v1 - mean) * rstd * g[col1] + be[col1];
        hF[(size_t)nd * 128 + col0] = o0;      hF[(size_t)nd * 128 + col1] = o1;
        hB[(size_t)nd * 128 + col0] = f2b(o0); hB[(size_t)nd * 128 + col1] = f2b(o1);
    }
}

// ---------------------------------------------------------------------------
// Aggregation: wave/node, 4 edge slots x 4-deep unroll (16 loads in flight).
// ---------------------------------------------------------------------------
__global__ __launch_bounds__(256) void aggregate_kernel(
    const unsigned short* __restrict__ hb, const int* __restrict__ offs,
    const int* __restrict__ csr, unsigned short* __restrict__ outp, int n, int E)
{
    const int node = blockIdx.x * 4 + (threadIdx.x >> 6);
    const int lane = threadIdx.x & 63;
    if (node >= n) return;
    const int e4 = lane >> 4;
    const int p  = lane & 15;
    const int s = offs[node];
    const int e = (node == n - 1) ? E : offs[node + 1];
    float a[8] = {};
    int i = s + e4;
    for (; i + 12 < e; i += 16) {
        const int d0 = csr[i], d1 = csr[i + 4], d2 = csr[i + 8], d3 = csr[i + 12];
        const uint4 u0 = *(const uint4*)(hb + (size_t)d0 * 128 + p * 8);
        const uint4 u1 = *(const uint4*)(hb + (size_t)d1 * 128 + p * 8);
        const uint4 u2 = *(const uint4*)(hb + (size_t)d2 * 128 + p * 8);
        const uint4 u3 = *(const uint4*)(hb + (size_t)d3 * 128 + p * 8);
        a[0] += blo(u0.x) + blo(u1.x) + blo(u2.x) + blo(u3.x);
        a[1] += bhi(u0.x) + bhi(u1.x) + bhi(u2.x) + bhi(u3.x);
        a[2] += blo(u0.y) + blo(u1.y) + blo(u2.y) + blo(u3.y);
        a[3] += bhi(u0.y) + bhi(u1.y) + bhi(u2.y) + bhi(u3.y);
        a[4] += blo(u0.z) + blo(u1.z) + blo(u2.z) + blo(u3.z);
        a[5] += bhi(u0.z) + bhi(u1.z) + bhi(u2.z) + bhi(u3.z);
        a[6] += blo(u0.w) + blo(u1.w) + blo(u2.w) + blo(u3.w);
        a[7] += bhi(u0.w) + bhi(u1.w) + bhi(u2.w) + bhi(u3.w);
    }
    for (; i < e; i += 4) {
        const uint4 u = *(const uint4*)(hb + (size_t)csr[i] * 128 + p * 8);
        a[0] += blo(u.x); a[1] += bhi(u.x);
        a[2] += blo(u.y); a[3] += bhi(u.y);
        a[4] += blo(u.z); a[5] += bhi(u.z);
        a[6] += blo(u.w); a[7] += bhi(u.w);
    }
    #pragma unroll
    for (int k = 0; k < 8; ++k) {
        a[k] += __shfl_xor(a[k], 16);
        a[k] += __shfl_xor(a[k], 32);
    }
    if (e4 == 0) {
        uint4 ow;
        ow.x = pk(a[0], a[1]); ow.y = pk(a[2], a[3]);
        ow.z = pk(a[4], a[5]); ow.w = pk(a[6], a[7]);
        *(uint4*)(outp + (size_t)node * 128 + p * 8) = ow;
    }
}

// ---------------------------------------------------------------------------
// Bucketed CSR build. (verified R4)
// ---------------------------------------------------------------------------
__global__ __launch_bounds__(256) void bcount_kernel(
    const int* __restrict__ esrc, int* __restrict__ bcnt, int E)
{
    __shared__ int hist[MAXB];
    for (int i = threadIdx.x; i < MAXB; i += 256) hist[i] = 0;
    __syncthreads();
    const int stride = gridDim.x * 256;
    for (int e = blockIdx.x * 256 + threadIdx.x; e < E; e += stride)
        atomicAdd(&hist[esrc[e] >> BSH], 1);
    __syncthreads();
    for (int i = threadIdx.x; i < MAXB; i += 256)
        if (hist[i]) atomicAdd(&bcnt[i], hist[i]);
}

__global__ void bscan_kernel(const int* __restrict__ bcnt, int* __restrict__ boffs,
                             int* __restrict__ bcur, int NB)
{
    if (threadIdx.x == 0 && blockIdx.x == 0) {
        int run = 0;
        for (int i = 0; i < NB; ++i) { boffs[i] = run; bcur[i] = run; run += bcnt[i]; }
        boffs[NB] = run;
    }
}

__global__ __launch_bounds__(256) void bscatter_kernel(
    const int* __restrict__ esrc, const int* __restrict__ edst,
    int* __restrict__ bcur, uint2* __restrict__ ebuck, int E)
{
    __shared__ int hist[MAXB], scanb[MAXB], lstart[MAXB], gbase[MAXB], cnt2[MAXB];
    __shared__ uint2 stage[2048];
    __shared__ int gaddr[2048];
    const int t = threadIdx.x;
    const int base = blockIdx.x * 2048;
    const int nchunk = min(2048, E - base);
    for (int i = t; i < MAXB; i += 256) { hist[i] = 0; cnt2[i] = 0; }
    __syncthreads();

    int es[8], ed[8], eb[8];
    #pragma unroll
    for (int i = 0; i < 8; ++i) {
        const int idx = base + i * 256 + t;
        if (idx < E) {
            es[i] = esrc[idx]; ed[i] = edst[idx];
            eb[i] = es[i] >> BSH;
            atomicAdd(&hist[eb[i]], 1);
        } else eb[i] = -1;
    }
    __syncthreads();

    if (t < MAXB) scanb[t] = hist[t];
    __syncthreads();
    for (int off = 1; off < MAXB; off <<= 1) {
        int v = 0;
        if (t < MAXB && t >= off) v = scanb[t - off];
        __syncthreads();
        if (t < MAXB) scanb[t] += v;
        __syncthreads();
    }
    if (t < MAXB) {
        lstart[t] = scanb[t] - hist[t];
        if (hist[t] > 0) gbase[t] = atomicAdd(&bcur[t], hist[t]);
    }
    __syncthreads();

    #pragma unroll
    for (int i = 0; i < 8; ++i) {
        if (eb[i] >= 0) {
            const int li = atomicAdd(&cnt2[eb[i]], 1);
            const int pos = lstart[eb[i]] + li;
            stage[pos] = make_uint2((unsigned)es[i], (unsigned)ed[i]);
            gaddr[pos] = gbase[eb[i]] + li;
        }
    }
    __syncthreads();
    for (int i = t; i < nchunk; i += 256)
        ebuck[gaddr[i]] = stage[i];
}

__global__ __launch_bounds__(256) void bbuild_kernel(
    const uint2* __restrict__ ebuck, const int* __restrict__ bcnt,
    const int* __restrict__ boffs, int* __restrict__ offs, int* __restrict__ csr, int N)
{
    __shared__ int degl[BW], sbuf[BW], curl[BW];
    const int b = blockIdx.x;
    const int t = threadIdx.x;
    const int nbase = b * BW;
    const int nn = min(BW, N - nbase);
    const int estart = boffs[b];
    const int ecnt = bcnt[b];

    for (int i = t; i < BW; i += 256) { degl[i] = 0; curl[i] = 0; }
    __syncthreads();
    for (int i = t; i < ecnt; i += 256)
        atomicAdd(&degl[(int)ebuck[estart + i].x - nbase], 1);
    __syncthreads();

    sbuf[t] = degl[t]; sbuf[t + 256] = degl[t + 256];
    __syncthreads();
    for (int off = 1; off < BW; off <<= 1) {
        const int i1 = t + 256;
        int v0 = (t  >= off) ? sbuf[t  - off] : 0;
        int v1 = (i1 >= off) ? sbuf[i1 - off] : 0;
        __syncthreads();
        sbuf[t] += v0; sbuf[i1] += v1;
        __syncthreads();
    }
    {
        const int e0 = sbuf[t] - degl[t];
        const int e1 = sbuf[t + 256] - degl[t + 256];
        sbuf[t] = e0; sbuf[t + 256] = e1;
        if (t < nn)       offs[nbase + t]       = estart + e0;
        if (t + 256 < nn) offs[nbase + t + 256] = estart + e1;
    }
    __syncthreads();
    for (int i = t; i < ecnt; i += 256) {
        const uint2 pr = ebuck[estart + i];
        const int s = (int)pr.x - nbase;
        const int pos = estart + sbuf[s] + atomicAdd(&curl[s], 1);
        csr[pos] = (int)pr.y;
    }
}

// ---------------------------------------------------------------------------
extern "C" void kernel_launch(void* const* d_in, const int* in_sizes, int n_in,
                              void* d_out, int out_size, void* d_ws, size_t ws_size,
                              hipStream_t stream)
{
    const float* x        = (const float*)d_in[0];
    const int*   samples  = (const int*)d_in[1];
    const int*   esrc     = (const int*)d_in[2];
    const int*   edst     = (const int*)d_in[3];
    const float* t_in_w   = (const float*)d_in[4];   // [3][384][128]
    const float* t_in_b   = (const float*)d_in[5];
    const float* t_out_w  = (const float*)d_in[6];   // [3][128][128]
    const float* t_out_b  = (const float*)d_in[7];
    const float* t_ffn_w1 = (const float*)d_in[8];   // [3][512][128]
    const float* t_ffn_b1 = (const float*)d_in[9];
    const float* t_ffn_w2 = (const float*)d_in[10];  // [3][128][512]
    const float* t_ffn_b2 = (const float*)d_in[11];
    const float* t_ln1_g  = (const float*)d_in[12];
    const float* t_ln1_b  = (const float*)d_in[13];
    const float* t_ln2_g  = (const float*)d_in[14];
    const float* t_ln2_b  = (const float*)d_in[15];
    const float* g_w      = (const float*)d_in[16];  // [2][128][256]
    const float* g_b      = (const float*)d_in[17];
    const float* g_ln_g   = (const float*)d_in[18];
    const float* g_ln_b   = (const float*)d_in[19];

    const int N = in_sizes[0] / DM;
    const int E = in_sizes[2];
    const int NB = (N + BW - 1) >> BSH;

    float* h = (float*)d_out;                        // [N][128] fp32 hidden

    // ---- workspace layout ----
    unsigned short* wbuf = (unsigned short*)d_ws;    // bf16 weights
    unsigned short* w_in  = wbuf;                    // 3*384*128 = 147456
    unsigned short* w_out = w_in  + 147456;          // 3*128*128 = 49152 (attn MFMA)
    unsigned short* w_f1  = w_out + 49152;           // 3*512*128 = 196608
    unsigned short* w_f2  = w_f1  + 196608;          // 3*128*512 = 196608
    unsigned short* w_g   = w_f2  + 196608;          // 2*128*256 = 65536
    unsigned* WoP = (unsigned*)(w_g + 65536);        // 3*8192 uints (unused now)
    unsigned short* hb  = (unsigned short*)(WoP + 3 * 8192);   // [N][128] bf16
    unsigned short* Bbf = hb  + (size_t)N * 128;     // [N][128] neigh
    unsigned short* Qbf = Bbf + (size_t)N * 128;     // [N][128] bf16 Q
    unsigned char*  kv8 = (unsigned char*)(Qbf + (size_t)N * 128);  // [N][256] fp8 K|V
    uint2* ebuck = (uint2*)(kv8 + (size_t)N * 256);  // [E]
    int* offs = (int*)(ebuck + E);                   // [N]
    int* csr  = offs + N;                            // [E]
    int* bcnt  = csr + E;                            // [MAXB]
    int* boffs = bcnt + MAXB;                        // [MAXB+1]
    int* bcur  = boffs + MAXB + 1;                   // [MAXB]

    const int mt  = (N + 63) / 64;
    const int mt2 = (N + 127) / 128;
    const int mtf = (N + 15) / 16;
    const dim3 blk(256);

    xcvt_kernel<<<((N * DM) / 4 + 255) / 256, blk, 0, stream>>>(x, h, hb, N * DM);
    setup_kernel<<<(163840 + 24576 + MAXB + 255) / 256, blk, 0, stream>>>(
        t_in_w, t_out_w, t_ffn_w1, t_ffn_w2, g_w, wbuf, WoP, bcnt);

    // ---- bucketed CSR build (bcnt zeroed by setup_kernel) ----
    bcount_kernel<<<(E + 2047) / 2048, blk, 0, stream>>>(esrc, bcnt, E);
    bscan_kernel<<<1, 64, 0, stream>>>(bcnt, boffs, bcur, NB);
    bscatter_kernel<<<(E + 2047) / 2048, blk, 0, stream>>>(esrc, edst, bcur, ebuck, E);
    bbuild_kernel<<<NB, blk, 0, stream>>>(ebuck, bcnt, boffs, offs, csr, N);

    const int pn_grid = (N + 3) / 4;

    for (int layer = 0; layer < 5; ++layer) {
        if (layer == 1 || layer == 3) {
            // -------- GNN block: split (R14 — fused variant was slower) -----
            const int i = (layer == 1) ? 0 : 1;
            aggregate_kernel<<<pn_grid, blk, 0, stream>>>(hb, offs, csr, Bbf, N, E);
            gemm_ln<256, true, 128><<<mt, blk, 0, stream>>>(
                hb, Bbf, w_g + (size_t)i * 32768, g_b + i * 128, h,
                g_ln_g + i * 128, g_ln_b + i * 128, h, hb, N);
        } else {
            // ---------------- Transformer block: 3 kernels ----------------
            const int i = (layer == 0) ? 0 : (layer == 2 ? 1 : 2);
            gemm_qkv<<<dim3(mt2, 6), blk, 0, stream>>>(
                hb, w_in + (size_t)i * 49152, t_in_b + i * 384, Qbf, kv8, N);
            attn_fused<<<pn_grid, blk, 0, stream>>>(
                Qbf, kv8, samples, w_out + (size_t)i * 16384, t_out_b + i * 128,
                t_ln1_g + i * 128, t_ln1_b + i * 128, h, hb, N);
            ffn_fused<<<mtf, blk, 0, stream>>>(
                hb, w_f1 + (size_t)i * 65536, t_ffn_b1 + i * 512,
                w_f2 + (size_t)i * 65536, t_ffn_b2 + i * 128, h,
                t_ln2_g + i * 128, t_ln2_b + i * 128, h, hb, N);
        }
    }
}

// Round 9
// 896.618 us; speedup vs baseline: 1.1904x; 1.1904x over previous
//
#include <hip/hip_runtime.h>

#define DM 128          // model dim
#define KS 20           // attention samples
#define BW 512          // CSR bucket width (nodes)
#define BSH 9           // log2(BW)
#define MAXB 128        // max buckets (N <= 65536)
#define HP 520          // padded LDS hidden row stride (ffn full-width), 16B-aligned

typedef __attribute__((ext_vector_type(8))) short short8;   // 8 bf16 (4 VGPRs)
typedef __attribute__((ext_vector_type(4))) float f32x4;
typedef __attribute__((ext_vector_type(2))) float f32x2;
typedef __attribute__((ext_vector_type(2))) __bf16 bf16x2;

__device__ __forceinline__ unsigned short f2b(float f) {
    unsigned u = __float_as_uint(f);
    u += 0x7fff + ((u >> 16) & 1);          // RNE
    return (unsigned short)(u >> 16);
}
__device__ __forceinline__ float b2f(unsigned short b) {
    return __uint_as_float(((unsigned)b) << 16);
}
__device__ __forceinline__ float blo(unsigned u) { return __uint_as_float(u << 16); }
__device__ __forceinline__ float bhi(unsigned u) { return __uint_as_float(u & 0xffff0000u); }
__device__ __forceinline__ unsigned pk(float a, float b) {
    return (unsigned)f2b(a) | ((unsigned)f2b(b) << 16);
}

// Packed bf16 dot-2 (HW v_dot2_f32_bf16 when available; fallback compile-safe)
#if __has_builtin(__builtin_amdgcn_fdot2_f32_bf16)
__device__ __forceinline__ float dot2bf(unsigned a, unsigned b, float acc) {
    return __builtin_amdgcn_fdot2_f32_bf16(
        __builtin_bit_cast(bf16x2, a), __builtin_bit_cast(bf16x2, b), acc, false);
}
#else
__device__ __forceinline__ float dot2bf(unsigned a, unsigned b, float acc) {
    return acc + blo(a) * blo(b) + bhi(a) * bhi(b);
}
#endif

// ---------------- fp8 e4m3 helpers (HW cvt on gfx950; SW fallback) ----------
__device__ __forceinline__ float f8dec_sw(unsigned char b) {
    const int s = b >> 7, e = (b >> 3) & 15, m = b & 7;
    float v = e ? ldexpf((float)(8 + m), e - 10) : ldexpf((float)m, -9);
    return s ? -v : v;
}
// decode 2 fp8 from low/high 16-bit word of u (HI must be compile-time const)
template <bool HI>
__device__ __forceinline__ f32x2 fp8x2(unsigned u) {
#if __has_builtin(__builtin_amdgcn_cvt_pk_f32_fp8)
    return __builtin_amdgcn_cvt_pk_f32_fp8(u, HI);
#else
    const unsigned w = HI ? (u >> 16) : (u & 0xffffu);
    return (f32x2){f8dec_sw((unsigned char)(w & 0xff)),
                   f8dec_sw((unsigned char)(w >> 8))};
#endif
}
__device__ __forceinline__ unsigned char f8enc(float v) {
#if __has_builtin(__builtin_amdgcn_cvt_pk_fp8_f32)
    return (unsigned char)(__builtin_amdgcn_cvt_pk_fp8_f32(v, v, 0, false) & 0xff);
#else
    unsigned u = __float_as_uint(v);
    unsigned s = (u >> 24) & 0x80;
    unsigned a = u & 0x7fffffffu;
    if (a >= 0x43e00000u) return (unsigned char)(s | 0x7e);   // clamp to 448
    if (a < 0x3c000000u) {                                    // subnormal (<2^-7 approx)
        int r = (int)(__uint_as_float(a) * 512.f + 0.5f);
        if (r > 7) return (unsigned char)(s | 0x08);
        return (unsigned char)(s | (unsigned)r);
    }
    unsigned r = a + 0x7ffffu + ((a >> 20) & 1);              // RNE at bit 20
    unsigned e = (r >> 23) - 120;
    unsigned m = (r >> 20) & 7;
    return (unsigned char)(s | (e << 3) | m);
#endif
}

// ---------------------------------------------------------------------------
// x -> h (fp32 copy) + hb (bf16), float4 wide
// ---------------------------------------------------------------------------
__global__ __launch_bounds__(256) void xcvt_kernel(
    const float* __restrict__ x, float* __restrict__ h,
    unsigned short* __restrict__ hb, int n)
{
    const int i = (blockIdx.x * 256 + threadIdx.x) * 4;
    if (i < n) {
        const float4 v = *(const float4*)(x + i);
        *(float4*)(h + i) = v;
        ((unsigned*)hb)[i / 2]     = pk(v.x, v.y);
        ((unsigned*)hb)[i / 2 + 1] = pk(v.z, v.w);
    }
}

// ---------------------------------------------------------------------------
// Merged setup (R15): weight bf16 convert + WoP repack + bcnt zero.
// ---------------------------------------------------------------------------
__global__ __launch_bounds__(256) void setup_kernel(
    const float* __restrict__ t_in_w,  const float* __restrict__ t_out_w,
    const float* __restrict__ t_ffn_w1, const float* __restrict__ t_ffn_w2,
    const float* __restrict__ g_w, unsigned short* __restrict__ wbuf,
    unsigned* __restrict__ WoP, int* __restrict__ bcnt)
{
    const int tid = blockIdx.x * 256 + threadIdx.x;
    if (tid < 163840) {
        const int i4 = tid * 4;
        const float* src; int rel;
        if      (i4 < 147456) { src = t_in_w;   rel = i4; }
        else if (i4 < 196608) { src = t_out_w;  rel = i4 - 147456; }
        else if (i4 < 393216) { src = t_ffn_w1; rel = i4 - 196608; }
        else if (i4 < 589824) { src = t_ffn_w2; rel = i4 - 393216; }
        else                  { src = g_w;      rel = i4 - 589824; }
        const float4 v = *(const float4*)(src + rel);
        ((unsigned*)wbuf)[i4 / 2]     = pk(v.x, v.y);
        ((unsigned*)wbuf)[i4 / 2 + 1] = pk(v.z, v.w);
    } else if (tid < 163840 + 24576) {
        const int t2 = tid - 163840;
        const int i = t2 / 8192, rem = t2 % 8192;
        const int plane = rem >> 12, r2 = rem & 4095;
        const int k2 = r2 >> 6, j = r2 & 63;
        const int col = j + plane * 64;
        const float* W = t_out_w + (size_t)i * 16384;   // [128][128]
        WoP[(size_t)i * 8192 + plane * 4096 + k2 * 64 + j] =
            pk(W[col * 128 + 2 * k2], W[col * 128 + 2 * k2 + 1]);
    } else if (tid < 163840 + 24576 + MAXB) {
        bcnt[tid - 163840 - 24576] = 0;
    }
}

// ---------------------------------------------------------------------------
// QKV GEMM (R16): out = X@W^T + bias, CI=128, CO=384.
// Band 0-1 (cols 0..127 = Q)   -> Qbf bf16 [N][128]
// Band 2-5 (cols 128..383 = KV)-> kv8 fp8 e4m3 [N][256] (K bytes 0-127, V 128-255)
// ---------------------------------------------------------------------------
__global__ __launch_bounds__(256) void gemm_qkv(
    const unsigned short* __restrict__ X,
    const unsigned short* __restrict__ W, const float* __restrict__ bias,
    unsigned short* __restrict__ Qbf, unsigned char* __restrict__ kv8, int M)
{
    const int tid  = threadIdx.x;
    const int wave = tid >> 6;
    const int lane = tid & 63;
    const int m0 = blockIdx.x * 128 + (wave >> 1) * 64;
    const int c0 = blockIdx.y * 64 + (wave & 1) * 32;
    const int lrow = lane & 15;
    const int quad = lane >> 4;

    f32x4 acc[4][2];
    #pragma unroll
    for (int i = 0; i < 4; ++i)
        #pragma unroll
        for (int j = 0; j < 2; ++j)
            acc[i][j] = (f32x4){0.f, 0.f, 0.f, 0.f};

    int rr[4]; bool vv[4];
    #pragma unroll
    for (int i = 0; i < 4; ++i) { rr[i] = m0 + i * 16 + lrow; vv[i] = rr[i] < M; }

    #pragma unroll
    for (int k0 = 0; k0 < 128; k0 += 32) {
        const int ko = k0 + quad * 8;
        short8 a[4];
        #pragma unroll
        for (int i = 0; i < 4; ++i) {
            a[i] = short8{};
            if (vv[i]) a[i] = *(const short8*)(X + (size_t)rr[i] * 128 + ko);
        }
        const short8 b0 = *(const short8*)(W + (size_t)(c0 + lrow) * 128 + ko);
        const short8 b1 = *(const short8*)(W + (size_t)(c0 + 16 + lrow) * 128 + ko);
        #pragma unroll
        for (int i = 0; i < 4; ++i) {
            acc[i][0] = __builtin_amdgcn_mfma_f32_16x16x32_bf16(a[i], b0, acc[i][0], 0, 0, 0);
            acc[i][1] = __builtin_amdgcn_mfma_f32_16x16x32_bf16(a[i], b1, acc[i][1], 0, 0, 0);
        }
    }

    const bool isQ = (c0 < 128);   // uniform per block (band granularity = 64 cols)
    #pragma unroll
    for (int i = 0; i < 4; ++i) {
        const int rb = m0 + i * 16 + quad * 4;
        #pragma unroll
        for (int j = 0; j < 2; ++j) {
            const int col = c0 + j * 16 + lrow;
            const float bsv = bias[col];
            #pragma unroll
            for (int r = 0; r < 4; ++r) {
                const int row = rb + r;
                if (row < M) {
                    const float v = acc[i][j][r] + bsv;
                    if (isQ) Qbf[(size_t)row * 128 + col] = f2b(v);
                    else     kv8[(size_t)row * 256 + (col - 128)] = f8enc(v);
                }
            }
        }
    }
}

// ---------------------------------------------------------------------------
// Fused GEMM(CO=128) + residual + LayerNorm. (verified R3-R8)
// ---------------------------------------------------------------------------
template <int CI, bool RELU, int SPLIT>
__global__ __launch_bounds__(256) void gemm_ln(
    const unsigned short* __restrict__ X0, const unsigned short* __restrict__ X1,
    const unsigned short* __restrict__ W, const float* __restrict__ bias,
    const float* __restrict__ resid,
    const float* __restrict__ g, const float* __restrict__ be,
    float* __restrict__ hF, unsigned short* __restrict__ hB, int M)
{
    __shared__ float psum[64][2][2];
    __shared__ float stats[64][2];

    const int tid  = threadIdx.x;
    const int wave = tid >> 6;
    const int lane = tid & 63;
    const int wr = (wave >> 1) * 32;
    const int wc = wave & 1;
    const int m0 = blockIdx.x * 64 + wr;
    const int c0 = wc * 64;
    const int lrow = lane & 15;
    const int quad = lane >> 4;

    f32x4 acc[2][4];
    #pragma unroll
    for (int i = 0; i < 2; ++i)
        #pragma unroll
        for (int j = 0; j < 4; ++j)
            acc[i][j] = (f32x4){0.f, 0.f, 0.f, 0.f};

    const int r0 = m0 + lrow;
    const int r1 = m0 + 16 + lrow;
    const bool v0 = r0 < M, v1 = r1 < M;

    for (int k0 = 0; k0 < CI; k0 += 32) {
        const unsigned short* xs;
        int kk, stride;
        if (SPLIT > 0 && k0 >= SPLIT) { xs = X1; kk = k0 - SPLIT; stride = CI - SPLIT; }
        else                          { xs = X0; kk = k0;         stride = (SPLIT > 0) ? SPLIT : CI; }
        const int ko = kk + quad * 8;
        short8 a0 = {}, a1 = {};
        if (v0) a0 = *(const short8*)(xs + (size_t)r0 * stride + ko);
        if (v1) a1 = *(const short8*)(xs + (size_t)r1 * stride + ko);
        const int kw = k0 + quad * 8;
        #pragma unroll
        for (int j = 0; j < 4; ++j) {
            const short8 bf = *(const short8*)(W + (size_t)(c0 + j * 16 + lrow) * CI + kw);
            acc[0][j] = __builtin_amdgcn_mfma_f32_16x16x32_bf16(a0, bf, acc[0][j], 0, 0, 0);
            acc[1][j] = __builtin_amdgcn_mfma_f32_16x16x32_bf16(a1, bf, acc[1][j], 0, 0, 0);
        }
    }

    float bcol[4], gcol[4], bec[4];
    #pragma unroll
    for (int j = 0; j < 4; ++j) {
        const int col = c0 + j * 16 + lrow;
        bcol[j] = bias[col];
        gcol[j] = g[col];
        bec[j]  = be[col];
    }

    float vals[2][4][4];
    #pragma unroll
    for (int i = 0; i < 2; ++i) {
        #pragma unroll
        for (int r = 0; r < 4; ++r) {
            const int lrel = wr + i * 16 + quad * 4 + r;
            const int row = blockIdx.x * 64 + lrel;
            const bool vr = row < M;
            float s = 0.f, s2 = 0.f;
            #pragma unroll
            for (int j = 0; j < 4; ++j) {
                const int col = c0 + j * 16 + lrow;
                float v = acc[i][j][r] + bcol[j];
                if (RELU) v = fmaxf(v, 0.f);
                if (vr) v += resid[(size_t)row * 128 + col];
                vals[i][j][r] = v;
                s += v; s2 += v * v;
            }
            s  += __shfl_xor(s, 1);  s  += __shfl_xor(s, 2);
            s  += __shfl_xor(s, 4);  s  += __shfl_xor(s, 8);
            s2 += __shfl_xor(s2, 1); s2 += __shfl_xor(s2, 2);
            s2 += __shfl_xor(s2, 4); s2 += __shfl_xor(s2, 8);
            if (lrow == 0) { psum[lrel][wc][0] = s; psum[lrel][wc][1] = s2; }
        }
    }
    __syncthreads();
    if (tid < 64) {
        const float sum   = psum[tid][0][0] + psum[tid][1][0];
        const float sumsq = psum[tid][0][1] + psum[tid][1][1];
        const float mean = sum * (1.f / 128.f);
        const float var  = sumsq * (1.f / 128.f) - mean * mean;
        stats[tid][0] = mean;
        stats[tid][1] = rsqrtf(var + 1e-5f);
    }
    __syncthreads();

    #pragma unroll
    for (int i = 0; i < 2; ++i) {
        #pragma unroll
        for (int r = 0; r < 4; ++r) {
            const int lrel = wr + i * 16 + quad * 4 + r;
            const int row = blockIdx.x * 64 + lrel;
            if (row < M) {
                const float mean = stats[lrel][0];
                const float rstd = stats[lrel][1];
                #pragma unroll
                for (int j = 0; j < 4; ++j) {
                    const int col = c0 + j * 16 + lrow;
                    const float o = (vals[i][j][r] - mean) * rstd * gcol[j] + bec[j];
                    hF[(size_t)row * 128 + col] = o;
                    hB[(size_t)row * 128 + col] = f2b(o);
                }
            }
        }
    }
}

// ---------------------------------------------------------------------------
// Fused FFN v6 (R20, verified ~79us): out = LN( relu(X@W1^T+b1)@W2^T + b2
// + resid ). Single full-width H buffer [32][520]; 1 barrier per block.
// (R22's 16-row v7 REGRESSED 79->116us: halving rows/block doubled per-
// dispatch weight re-reads (400->800MB L2). Rows/block is a weight-
// amortization knob first, occupancy knob second.)
// ---------------------------------------------------------------------------
__global__ __launch_bounds__(256, 4) void ffn_fused(
    const unsigned short* __restrict__ X,    // [M][128] bf16
    const unsigned short* __restrict__ W1,   // [512][128]
    const float* __restrict__ b1,
    const unsigned short* __restrict__ W2,   // [128][512]
    const float* __restrict__ b2,
    const float* __restrict__ resid,
    const float* __restrict__ g, const float* __restrict__ be,
    float* __restrict__ hF, unsigned short* __restrict__ hB, int M)
{
    __shared__ unsigned short Hs[32 * HP];   // 33.3 KB full-width hidden buffer
    __shared__ float psum[32][4][2];
    __shared__ float stats[32][2];

    const int tid  = threadIdx.x;
    const int wave = tid >> 6;
    const int lane = tid & 63;
    const int lrow = lane & 15;
    const int quad = lane >> 4;
    const int m0 = blockIdx.x * 32;

    const int c0 = wave * 32;                // phase-2 col base (32 cols/wave)

    const int r0 = m0 + lrow;
    const int r1 = m0 + 16 + lrow;
    const bool v0 = r0 < M, v1 = r1 < M;

    // ---- hoisted X fragment loads: 8 x short8, all K, both row-frags ----
    short8 xa[4], xb[4];
    #pragma unroll
    for (int k = 0; k < 4; ++k) {
        const int ko = k * 32 + quad * 8;
        xa[k] = short8{}; xb[k] = short8{};
        if (v0) xa[k] = *(const short8*)(X + (size_t)r0 * 128 + ko);
        if (v1) xb[k] = *(const short8*)(X + (size_t)r1 * 128 + ko);
    }

    // ---- hoisted residual loads (own rows only; in-place safe) ----
    float res[2][4][2];
    #pragma unroll
    for (int i = 0; i < 2; ++i)
        #pragma unroll
        for (int r = 0; r < 4; ++r) {
            const int row = m0 + i * 16 + quad * 4 + r;
            const bool vr = row < M;
            #pragma unroll
            for (int j = 0; j < 2; ++j)
                res[i][r][j] = vr ? resid[(size_t)row * 128 + c0 + j * 16 + lrow] : 0.f;
        }

    // ---- phase 1: all 512 hidden cols, no intervening barrier ----
    #pragma unroll
    for (int half = 0; half < 2; ++half) {
        const int cb = half * 256 + wave * 64;    // global hidden col base
        f32x4 acc[2][4];
        #pragma unroll
        for (int i = 0; i < 2; ++i)
            #pragma unroll
            for (int j = 0; j < 4; ++j)
                acc[i][j] = (f32x4){0.f, 0.f, 0.f, 0.f};

        #pragma unroll
        for (int k = 0; k < 4; ++k) {
            const int ko = k * 32 + quad * 8;
            #pragma unroll
            for (int j = 0; j < 4; ++j) {
                const short8 bf = *(const short8*)(W1 + (size_t)(cb + j * 16 + lrow) * 128 + ko);
                acc[0][j] = __builtin_amdgcn_mfma_f32_16x16x32_bf16(xa[k], bf, acc[0][j], 0, 0, 0);
                acc[1][j] = __builtin_amdgcn_mfma_f32_16x16x32_bf16(xb[k], bf, acc[1][j], 0, 0, 0);
            }
        }
        float bc[4];
        #pragma unroll
        for (int j = 0; j < 4; ++j) bc[j] = b1[cb + j * 16 + lrow];
        #pragma unroll
        for (int i = 0; i < 2; ++i) {
            #pragma unroll
            for (int r = 0; r < 4; ++r) {
                const int lrel = i * 16 + quad * 4 + r;
                #pragma unroll
                for (int j = 0; j < 4; ++j)
                    Hs[lrel * HP + cb + j * 16 + lrow] =
                        f2b(fmaxf(acc[i][j][r] + bc[j], 0.f));
            }
        }
    }
    __syncthreads();

    // ---- phase 2: full K=512 accumulation in one chain ----
    f32x4 acc2[2][2];
    #pragma unroll
    for (int i = 0; i < 2; ++i)
        #pragma unroll
        for (int j = 0; j < 2; ++j)
            acc2[i][j] = (f32x4){0.f, 0.f, 0.f, 0.f};

    #pragma unroll
    for (int k0 = 0; k0 < 512; k0 += 32) {
        const int ko = k0 + quad * 8;
        const short8 a0 = *(const short8*)&Hs[lrow * HP + ko];
        const short8 a1 = *(const short8*)&Hs[(16 + lrow) * HP + ko];
        #pragma unroll
        for (int j = 0; j < 2; ++j) {
            const short8 bf = *(const short8*)(W2 + (size_t)(c0 + j * 16 + lrow) * 512 + ko);
            acc2[0][j] = __builtin_amdgcn_mfma_f32_16x16x32_bf16(a0, bf, acc2[0][j], 0, 0, 0);
            acc2[1][j] = __builtin_amdgcn_mfma_f32_16x16x32_bf16(a1, bf, acc2[1][j], 0, 0, 0);
        }
    }

    float bcol[2], gcol[2], bec[2];
    #pragma unroll
    for (int j = 0; j < 2; ++j) {
        const int col = c0 + j * 16 + lrow;
        bcol[j] = b2[col];
        gcol[j] = g[col];
        bec[j]  = be[col];
    }

    float vals[2][2][4];
    #pragma unroll
    for (int i = 0; i < 2; ++i) {
        #pragma unroll
        for (int r = 0; r < 4; ++r) {
            const int lrel = i * 16 + quad * 4 + r;
            const int row = m0 + lrel;
            float s = 0.f, s2 = 0.f;
            #pragma unroll
            for (int j = 0; j < 2; ++j) {
                float v = acc2[i][j][r] + bcol[j] + res[i][r][j];
                vals[i][j][r] = v;
                s += v; s2 += v * v;
            }
            s  += __shfl_xor(s, 1);  s  += __shfl_xor(s, 2);
            s  += __shfl_xor(s, 4);  s  += __shfl_xor(s, 8);
            s2 += __shfl_xor(s2, 1); s2 += __shfl_xor(s2, 2);
            s2 += __shfl_xor(s2, 4); s2 += __shfl_xor(s2, 8);
            if (lrow == 0) { psum[lrel][wave][0] = s; psum[lrel][wave][1] = s2; }
        }
    }
    __syncthreads();
    if (tid < 32) {
        const float sum   = psum[tid][0][0] + psum[tid][1][0] + psum[tid][2][0] + psum[tid][3][0];
        const float sumsq = psum[tid][0][1] + psum[tid][1][1] + psum[tid][2][1] + psum[tid][3][1];
        const float mean = sum * (1.f / 128.f);
        const float var  = sumsq * (1.f / 128.f) - mean * mean;
        stats[tid][0] = mean;
        stats[tid][1] = rsqrtf(var + 1e-5f);
    }
    __syncthreads();

    #pragma unroll
    for (int i = 0; i < 2; ++i) {
        #pragma unroll
        for (int r = 0; r < 4; ++r) {
            const int lrel = i * 16 + quad * 4 + r;
            const int row = m0 + lrel;
            if (row < M) {
                const float mean = stats[lrel][0];
                const float rstd = stats[lrel][1];
                #pragma unroll
                for (int j = 0; j < 2; ++j) {
                    const int col = c0 + j * 16 + lrow;
                    const float o = (vals[i][j][r] - mean) * rstd * gcol[j] + bec[j];
                    hF[(size_t)row * 128 + col] = o;
                    hB[(size_t)row * 128 + col] = f2b(o);
                }
            }
        }
    }
}

// ---------------------------------------------------------------------------
// attn_fused (R23): R19 verified body (fp8 KV gather + MFMA out-proj with
// padded ctxs + replicated-row all-lane epilogue) wrapped in a GRID-STRIDE
// loop. R19 counters: occupancy 60% with VGPR=40/LDS=1.5KB (resources allow
// 100%) — 12500 short-lived blocks leave CUs under-filled at block turnover.
// Launch exactly 2048 blocks (8/CU); each iterates node-groups. Cross-
// iteration LDS hazards (ctxs/psum/stats) each separated by >=1 barrier.
// ---------------------------------------------------------------------------
__global__ __launch_bounds__(256) void attn_fused(
    const unsigned short* __restrict__ qbf,   // [N][128] bf16 Q
    const unsigned char* __restrict__ kv8,    // [N][256] fp8 (K 0-127 | V 128-255)
    const int* __restrict__ samples,
    const unsigned short* __restrict__ Wo,    // [128 col][128 k] bf16 out-proj
    const float* __restrict__ bo,
    const float* __restrict__ g, const float* __restrict__ be,
    float* __restrict__ hF, unsigned short* __restrict__ hB, int n)
{
    __shared__ unsigned ctxs[4][68];    // padded: rows on distinct bank groups
    __shared__ float psum[4][4][2];     // [node][wave][sum,sumsq]
    __shared__ float stats[4][2];
    const int wv = threadIdx.x >> 6;
    const int lane = threadIdx.x & 63;
    const int s4 = lane >> 4;
    const int p  = lane & 15;
    const float scale = 0.17677669529663687f;  // 1/sqrt(32)

    const int ngroups = (n + 3) >> 2;

    for (int grp = blockIdx.x; grp < ngroups; grp += gridDim.x) {

    const int node0 = grp * 4 + wv;
    const bool live = node0 < n;
    const int node = live ? node0 : (n - 1);   // clamp; stores guarded

    // ---- epilogue identity for this lane: node = quad (replicated C rows) --
    const int nd = grp * 4 + s4;
    const bool alive = nd < n;
    const int col0 = wv * 32 + p;
    const int col1 = wv * 32 + 16 + p;
    // prefetch own-node residual (consumed after MFMA; in-place safe)
    float res0 = 0.f, res1 = 0.f;
    if (alive) {
        res0 = hF[(size_t)nd * 128 + col0];
        res1 = hF[(size_t)nd * 128 + col1];
    }

    const uint4 qu = *(const uint4*)(qbf + (size_t)node * 128 + p * 8);

    int rows[5];
    #pragma unroll
    for (int jj = 0; jj < 5; ++jj)
        rows[jj] = samples[node * KS + jj * 4 + s4];

    uint2 kus[5], vus[5];
    #pragma unroll
    for (int jj = 0; jj < 5; ++jj) {
        const unsigned char* rb = kv8 + (size_t)rows[jj] * 256 + p * 8;
        kus[jj] = *(const uint2*)rb;            // k dims 8p..8p+7 (fp8)
        vus[jj] = *(const uint2*)(rb + 128);    // v dims 8p..8p+7 (fp8)
    }

    // unpack own q once (dims 8p..8p+7)
    const float q0 = blo(qu.x), q1 = bhi(qu.x), q2 = blo(qu.y), q3 = bhi(qu.y);
    const float q4 = blo(qu.z), q5 = bhi(qu.z), q6 = blo(qu.w), q7 = bhi(qu.w);

    float sc[5];
    #pragma unroll
    for (int jj = 0; jj < 5; ++jj) {
        const f32x2 k0 = fp8x2<false>(kus[jj].x);   // dims 8p,   8p+1
        const f32x2 k1 = fp8x2<true >(kus[jj].x);   // dims 8p+2, 8p+3
        const f32x2 k2 = fp8x2<false>(kus[jj].y);   // dims 8p+4, 8p+5
        const f32x2 k3 = fp8x2<true >(kus[jj].y);   // dims 8p+6, 8p+7
        float d = q0 * k0.x;
        d = fmaf(q1, k0.y, d); d = fmaf(q2, k1.x, d); d = fmaf(q3, k1.y, d);
        d = fmaf(q4, k2.x, d); d = fmaf(q5, k2.y, d);
        d = fmaf(q6, k3.x, d); d = fmaf(q7, k3.y, d);
        d += __shfl_xor(d, 1);
        d += __shfl_xor(d, 2);
        sc[jj] = d * scale;
    }

    float m = sc[0];
    #pragma unroll
    for (int jj = 1; jj < 5; ++jj) m = fmaxf(m, sc[jj]);
    m = fmaxf(m, __shfl_xor(m, 16));
    m = fmaxf(m, __shfl_xor(m, 32));

    float l = 0.f;
    float o[8] = {};
    #pragma unroll
    for (int jj = 0; jj < 5; ++jj) {
        const float e = __expf(sc[jj] - m);
        l += e;
        const f32x2 v0 = fp8x2<false>(vus[jj].x);
        const f32x2 v1 = fp8x2<true >(vus[jj].x);
        const f32x2 v2 = fp8x2<false>(vus[jj].y);
        const f32x2 v3 = fp8x2<true >(vus[jj].y);
        o[0] = fmaf(e, v0.x, o[0]); o[1] = fmaf(e, v0.y, o[1]);
        o[2] = fmaf(e, v1.x, o[2]); o[3] = fmaf(e, v1.y, o[3]);
        o[4] = fmaf(e, v2.x, o[4]); o[5] = fmaf(e, v2.y, o[5]);
        o[6] = fmaf(e, v3.x, o[6]); o[7] = fmaf(e, v3.y, o[7]);
    }

    l += __shfl_xor(l, 16); l += __shfl_xor(l, 32);
    #pragma unroll
    for (int i = 0; i < 8; ++i) {
        o[i] += __shfl_xor(o[i], 16);
        o[i] += __shfl_xor(o[i], 32);
    }

    const float inv = 1.f / l;
    if (s4 == 0) {
        #pragma unroll
        for (int i = 0; i < 4; ++i)
            ctxs[wv][p * 4 + i] = pk(o[2 * i] * inv, o[2 * i + 1] * inv);
    }
    __syncthreads();

    // ---- out-proj via MFMA: rows 0-15 replicate nodes 0-3 ----
    // A-frag: lane row = p, supplies ctx[p&3], k = kt*32 + s4*8 .. +7
    // B-frag: col = wv*32 + j*16 + p, k consecutive (Wo row-major [col][k])
    f32x4 acc[2];
    acc[0] = (f32x4){0.f, 0.f, 0.f, 0.f};
    acc[1] = (f32x4){0.f, 0.f, 0.f, 0.f};
    #pragma unroll
    for (int kt = 0; kt < 4; ++kt) {
        const uint4 av = *(const uint4*)&ctxs[p & 3][kt * 16 + s4 * 4];
        const short8 af = __builtin_bit_cast(short8, av);
        #pragma unroll
        for (int j = 0; j < 2; ++j) {
            const int cb = wv * 32 + j * 16;
            const short8 bf = *(const short8*)(Wo + (size_t)(cb + p) * 128 + kt * 32 + s4 * 8);
            acc[j] = __builtin_amdgcn_mfma_f32_16x16x32_bf16(af, bf, acc[j], 0, 0, 0);
        }
    }

    // ---- all-lane epilogue: C row s4*4+r = node r; this lane keeps r = s4 --
    const float a0 = (s4 == 0) ? acc[0][0] : (s4 == 1) ? acc[0][1]
                   : (s4 == 2) ? acc[0][2] : acc[0][3];
    const float a1 = (s4 == 0) ? acc[1][0] : (s4 == 1) ? acc[1][1]
                   : (s4 == 2) ? acc[1][2] : acc[1][3];
    const float v0 = a0 + bo[col0] + res0;
    const float v1 = a1 + bo[col1] + res1;
    float s  = v0 + v1;
    float s2 = v0 * v0 + v1 * v1;
    s  += __shfl_xor(s, 1);  s  += __shfl_xor(s, 2);
    s  += __shfl_xor(s, 4);  s  += __shfl_xor(s, 8);
    s2 += __shfl_xor(s2, 1); s2 += __shfl_xor(s2, 2);
    s2 += __shfl_xor(s2, 4); s2 += __shfl_xor(s2, 8);
    if (p == 0) { psum[s4][wv][0] = s; psum[s4][wv][1] = s2; }
    __syncthreads();
    if (threadIdx.x < 4) {
        const int r = threadIdx.x;
        const float sum   = psum[r][0][0] + psum[r][1][0] + psum[r][2][0] + psum[r][3][0];
        const float sumsq = psum[r][0][1] + psum[r][1][1] + psum[r][2][1] + psum[r][3][1];
        const float mean = sum * (1.f / 128.f);
        const float var  = sumsq * (1.f / 128.f) - mean * mean;
        stats[r][0] = mean;
        stats[r][1] = rsqrtf(var + 1e-5f);
    }
    __syncthreads();
    if (alive) {
        const float mean = stats[s4][0];
        const float rstd = stats[s4][1];
        const float o0 = (v0 - mean) * rstd * g[col0] + be[col0];
        const float o1 = (v1 - mean) * rstd * g[col1] + be[col1];
        hF[(size_t)nd * 128 + col0] = o0;      hF[(size_t)nd * 128 + col1] = o1;
        hB[(size_t)nd * 128 + col0] = f2b(o0); hB[(size_t)nd * 128 + col1] = f2b(o1);
    }
    __syncthreads();   // protect stats/ctxs before next iteration's writes

    }   // grid-stride loop
}

// ---------------------------------------------------------------------------
// Aggregation: wave/node, 4 edge slots x 4-deep unroll (16 loads in flight).
// ---------------------------------------------------------------------------
__global__ __launch_bounds__(256) void aggregate_kernel(
    const unsigned short* __restrict__ hb, const int* __restrict__ offs,
    const int* __restrict__ csr, unsigned short* __restrict__ outp, int n, int E)
{
    const int node = blockIdx.x * 4 + (threadIdx.x >> 6);
    const int lane = threadIdx.x & 63;
    if (node >= n) return;
    const int e4 = lane >> 4;
    const int p  = lane & 15;
    const int s = offs[node];
    const int e = (node == n - 1) ? E : offs[node + 1];
    float a[8] = {};
    int i = s + e4;
    for (; i + 12 < e; i += 16) {
        const int d0 = csr[i], d1 = csr[i + 4], d2 = csr[i + 8], d3 = csr[i + 12];
        const uint4 u0 = *(const uint4*)(hb + (size_t)d0 * 128 + p * 8);
        const uint4 u1 = *(const uint4*)(hb + (size_t)d1 * 128 + p * 8);
        const uint4 u2 = *(const uint4*)(hb + (size_t)d2 * 128 + p * 8);
        const uint4 u3 = *(const uint4*)(hb + (size_t)d3 * 128 + p * 8);
        a[0] += blo(u0.x) + blo(u1.x) + blo(u2.x) + blo(u3.x);
        a[1] += bhi(u0.x) + bhi(u1.x) + bhi(u2.x) + bhi(u3.x);
        a[2] += blo(u0.y) + blo(u1.y) + blo(u2.y) + blo(u3.y);
        a[3] += bhi(u0.y) + bhi(u1.y) + bhi(u2.y) + bhi(u3.y);
        a[4] += blo(u0.z) + blo(u1.z) + blo(u2.z) + blo(u3.z);
        a[5] += bhi(u0.z) + bhi(u1.z) + bhi(u2.z) + bhi(u3.z);
        a[6] += blo(u0.w) + blo(u1.w) + blo(u2.w) + blo(u3.w);
        a[7] += bhi(u0.w) + bhi(u1.w) + bhi(u2.w) + bhi(u3.w);
    }
    for (; i < e; i += 4) {
        const uint4 u = *(const uint4*)(hb + (size_t)csr[i] * 128 + p * 8);
        a[0] += blo(u.x); a[1] += bhi(u.x);
        a[2] += blo(u.y); a[3] += bhi(u.y);
        a[4] += blo(u.z); a[5] += bhi(u.z);
        a[6] += blo(u.w); a[7] += bhi(u.w);
    }
    #pragma unroll
    for (int k = 0; k < 8; ++k) {
        a[k] += __shfl_xor(a[k], 16);
        a[k] += __shfl_xor(a[k], 32);
    }
    if (e4 == 0) {
        uint4 ow;
        ow.x = pk(a[0], a[1]); ow.y = pk(a[2], a[3]);
        ow.z = pk(a[4], a[5]); ow.w = pk(a[6], a[7]);
        *(uint4*)(outp + (size_t)node * 128 + p * 8) = ow;
    }
}

// ---------------------------------------------------------------------------
// Bucketed CSR build. (verified R4)
// ---------------------------------------------------------------------------
__global__ __launch_bounds__(256) void bcount_kernel(
    const int* __restrict__ esrc, int* __restrict__ bcnt, int E)
{
    __shared__ int hist[MAXB];
    for (int i = threadIdx.x; i < MAXB; i += 256) hist[i] = 0;
    __syncthreads();
    const int stride = gridDim.x * 256;
    for (int e = blockIdx.x * 256 + threadIdx.x; e < E; e += stride)
        atomicAdd(&hist[esrc[e] >> BSH], 1);
    __syncthreads();
    for (int i = threadIdx.x; i < MAXB; i += 256)
        if (hist[i]) atomicAdd(&bcnt[i], hist[i]);
}

__global__ void bscan_kernel(const int* __restrict__ bcnt, int* __restrict__ boffs,
                             int* __restrict__ bcur, int NB)
{
    if (threadIdx.x == 0 && blockIdx.x == 0) {
        int run = 0;
        for (int i = 0; i < NB; ++i) { boffs[i] = run; bcur[i] = run; run += bcnt[i]; }
        boffs[NB] = run;
    }
}

__global__ __launch_bounds__(256) void bscatter_kernel(
    const int* __restrict__ esrc, const int* __restrict__ edst,
    int* __restrict__ bcur, uint2* __restrict__ ebuck, int E)
{
    __shared__ int hist[MAXB], scanb[MAXB], lstart[MAXB], gbase[MAXB], cnt2[MAXB];
    __shared__ uint2 stage[2048];
    __shared__ int gaddr[2048];
    const int t = threadIdx.x;
    const int base = blockIdx.x * 2048;
    const int nchunk = min(2048, E - base);
    for (int i = t; i < MAXB; i += 256) { hist[i] = 0; cnt2[i] = 0; }
    __syncthreads();

    int es[8], ed[8], eb[8];
    #pragma unroll
    for (int i = 0; i < 8; ++i) {
        const int idx = base + i * 256 + t;
        if (idx < E) {
            es[i] = esrc[idx]; ed[i] = edst[idx];
            eb[i] = es[i] >> BSH;
            atomicAdd(&hist[eb[i]], 1);
        } else eb[i] = -1;
    }
    __syncthreads();

    if (t < MAXB) scanb[t] = hist[t];
    __syncthreads();
    for (int off = 1; off < MAXB; off <<= 1) {
        int v = 0;
        if (t < MAXB && t >= off) v = scanb[t - off];
        __syncthreads();
        if (t < MAXB) scanb[t] += v;
        __syncthreads();
    }
    if (t < MAXB) {
        lstart[t] = scanb[t] - hist[t];
        if (hist[t] > 0) gbase[t] = atomicAdd(&bcur[t], hist[t]);
    }
    __syncthreads();

    #pragma unroll
    for (int i = 0; i < 8; ++i) {
        if (eb[i] >= 0) {
            const int li = atomicAdd(&cnt2[eb[i]], 1);
            const int pos = lstart[eb[i]] + li;
            stage[pos] = make_uint2((unsigned)es[i], (unsigned)ed[i]);
            gaddr[pos] = gbase[eb[i]] + li;
        }
    }
    __syncthreads();
    for (int i = t; i < nchunk; i += 256)
        ebuck[gaddr[i]] = stage[i];
}

__global__ __launch_bounds__(256) void bbuild_kernel(
    const uint2* __restrict__ ebuck, const int* __restrict__ bcnt,
    const int* __restrict__ boffs, int* __restrict__ offs, int* __restrict__ csr, int N)
{
    __shared__ int degl[BW], sbuf[BW], curl[BW];
    const int b = blockIdx.x;
    const int t = threadIdx.x;
    const int nbase = b * BW;
    const int nn = min(BW, N - nbase);
    const int estart = boffs[b];
    const int ecnt = bcnt[b];

    for (int i = t; i < BW; i += 256) { degl[i] = 0; curl[i] = 0; }
    __syncthreads();
    for (int i = t; i < ecnt; i += 256)
        atomicAdd(&degl[(int)ebuck[estart + i].x - nbase], 1);
    __syncthreads();

    sbuf[t] = degl[t]; sbuf[t + 256] = degl[t + 256];
    __syncthreads();
    for (int off = 1; off < BW; off <<= 1) {
        const int i1 = t + 256;
        int v0 = (t  >= off) ? sbuf[t  - off] : 0;
        int v1 = (i1 >= off) ? sbuf[i1 - off] : 0;
        __syncthreads();
        sbuf[t] += v0; sbuf[i1] += v1;
        __syncthreads();
    }
    {
        const int e0 = sbuf[t] - degl[t];
        const int e1 = sbuf[t + 256] - degl[t + 256];
        sbuf[t] = e0; sbuf[t + 256] = e1;
        if (t < nn)       offs[nbase + t]       = estart + e0;
        if (t + 256 < nn) offs[nbase + t + 256] = estart + e1;
    }
    __syncthreads();
    for (int i = t; i < ecnt; i += 256) {
        const uint2 pr = ebuck[estart + i];
        const int s = (int)pr.x - nbase;
        const int pos = estart + sbuf[s] + atomicAdd(&curl[s], 1);
        csr[pos] = (int)pr.y;
    }
}

// ---------------------------------------------------------------------------
extern "C" void kernel_launch(void* const* d_in, const int* in_sizes, int n_in,
                              void* d_out, int out_size, void* d_ws, size_t ws_size,
                              hipStream_t stream)
{
    const float* x        = (const float*)d_in[0];
    const int*   samples  = (const int*)d_in[1];
    const int*   esrc     = (const int*)d_in[2];
    const int*   edst     = (const int*)d_in[3];
    const float* t_in_w   = (const float*)d_in[4];   // [3][384][128]
    const float* t_in_b   = (const float*)d_in[5];
    const float* t_out_w  = (const float*)d_in[6];   // [3][128][128]
    const float* t_out_b  = (const float*)d_in[7];
    const float* t_ffn_w1 = (const float*)d_in[8];   // [3][512][128]
    const float* t_ffn_b1 = (const float*)d_in[9];
    const float* t_ffn_w2 = (const float*)d_in[10];  // [3][128][512]
    const float* t_ffn_b2 = (const float*)d_in[11];
    const float* t_ln1_g  = (const float*)d_in[12];
    const float* t_ln1_b  = (const float*)d_in[13];
    const float* t_ln2_g  = (const float*)d_in[14];
    const float* t_ln2_b  = (const float*)d_in[15];
    const float* g_w      = (const float*)d_in[16];  // [2][128][256]
    const float* g_b      = (const float*)d_in[17];
    const float* g_ln_g   = (const float*)d_in[18];
    const float* g_ln_b   = (const float*)d_in[19];

    const int N = in_sizes[0] / DM;
    const int E = in_sizes[2];
    const int NB = (N + BW - 1) >> BSH;

    float* h = (float*)d_out;                        // [N][128] fp32 hidden

    // ---- workspace layout ----
    unsigned short* wbuf = (unsigned short*)d_ws;    // bf16 weights
    unsigned short* w_in  = wbuf;                    // 3*384*128 = 147456
    unsigned short* w_out = w_in  + 147456;          // 3*128*128 = 49152 (attn MFMA)
    unsigned short* w_f1  = w_out + 49152;           // 3*512*128 = 196608
    unsigned short* w_f2  = w_f1  + 196608;          // 3*128*512 = 196608
    unsigned short* w_g   = w_f2  + 196608;          // 2*128*256 = 65536
    unsigned* WoP = (unsigned*)(w_g + 65536);        // 3*8192 uints (unused now)
    unsigned short* hb  = (unsigned short*)(WoP + 3 * 8192);   // [N][128] bf16
    unsigned short* Bbf = hb  + (size_t)N * 128;     // [N][128] neigh
    unsigned short* Qbf = Bbf + (size_t)N * 128;     // [N][128] bf16 Q
    unsigned char*  kv8 = (unsigned char*)(Qbf + (size_t)N * 128);  // [N][256] fp8 K|V
    uint2* ebuck = (uint2*)(kv8 + (size_t)N * 256);  // [E]
    int* offs = (int*)(ebuck + E);                   // [N]
    int* csr  = offs + N;                            // [E]
    int* bcnt  = csr + E;                            // [MAXB]
    int* boffs = bcnt + MAXB;                        // [MAXB+1]
    int* bcur  = boffs + MAXB + 1;                   // [MAXB]

    const int mt  = (N + 63) / 64;
    const int mt2 = (N + 127) / 128;
    const int mtf = (N + 31) / 32;
    const dim3 blk(256);

    xcvt_kernel<<<((N * DM) / 4 + 255) / 256, blk, 0, stream>>>(x, h, hb, N * DM);
    setup_kernel<<<(163840 + 24576 + MAXB + 255) / 256, blk, 0, stream>>>(
        t_in_w, t_out_w, t_ffn_w1, t_ffn_w2, g_w, wbuf, WoP, bcnt);

    // ---- bucketed CSR build (bcnt zeroed by setup_kernel) ----
    bcount_kernel<<<(E + 2047) / 2048, blk, 0, stream>>>(esrc, bcnt, E);
    bscan_kernel<<<1, 64, 0, stream>>>(bcnt, boffs, bcur, NB);
    bscatter_kernel<<<(E + 2047) / 2048, blk, 0, stream>>>(esrc, edst, bcur, ebuck, E);
    bbuild_kernel<<<NB, blk, 0, stream>>>(ebuck, bcnt, boffs, offs, csr, N);

    const int pn_grid = (N + 3) / 4;
    const int attn_grid = 2048;          // 8 blocks/CU, grid-stride inside

    for (int layer = 0; layer < 5; ++layer) {
        if (layer == 1 || layer == 3) {
            // -------- GNN block: split (R14 — fused variant was slower) -----
            const int i = (layer == 1) ? 0 : 1;
            aggregate_kernel<<<pn_grid, blk, 0, stream>>>(hb, offs, csr, Bbf, N, E);
            gemm_ln<256, true, 128><<<mt, blk, 0, stream>>>(
                hb, Bbf, w_g + (size_t)i * 32768, g_b + i * 128, h,
                g_ln_g + i * 128, g_ln_b + i * 128, h, hb, N);
        } else {
            // ---------------- Transformer block: 3 kernels ----------------
            const int i = (layer == 0) ? 0 : (layer == 2 ? 1 : 2);
            gemm_qkv<<<dim3(mt2, 6), blk, 0, stream>>>(
                hb, w_in + (size_t)i * 49152, t_in_b + i * 384, Qbf, kv8, N);
            attn_fused<<<attn_grid, blk, 0, stream>>>(
                Qbf, kv8, samples, w_out + (size_t)i * 16384, t_out_b + i * 128,
                t_ln1_g + i * 128, t_ln1_b + i * 128, h, hb, N);
            ffn_fused<<<mtf, blk, 0, stream>>>(
                hb, w_f1 + (size_t)i * 65536, t_ffn_b1 + i * 512,
                w_f2 + (size_t)i * 65536, t_ffn_b2 + i * 128, h,
                t_ln2_g + i * 128, t_ln2_b + i * 128, h, hb, N);
        }
    }
}